// Round 7
// baseline (166.418 us; speedup 1.0000x reference)
//
#include <hip/hip_runtime.h>

#define N_NODES_C   524288
#define N_EDGES_C   786432
#define NUM_GRAPHS_C 8192
#define NT 16          // NUM_NODE_TYPES
#define NODE_DIM_C 256
#define EDGE_DIM_C 128
#define HDIM 384       // NODE_DIM + EDGE_DIM
#define KC 48          // folded inner dim: 16 (node) + 32 (edge)

#define FOLD_BLOCKS  72            // ceil(KC*HDIM / 256)
#define MEAN_BLOCKS  4096          // 2048 edge + 2048 node, parity-interleaved
#define TOTAL_BLOCKS (FOLD_BLOCKS + MEAN_BLOCKS)

// ---------------- workspace layout (bytes) ----------------
#define WS_NM    0                  // float[8192*16]   (node means)
#define WS_EM    524288             // float[8192*32]   (edge means)
#define WS_WC    1572864            // float[48*384]    (folded weights)

__device__ __forceinline__ int lower_bound_i32(const int* __restrict__ a, int n, int key) {
    int lo = 0, hi = n;
    while (lo < hi) {
        int mid = (lo + hi) >> 1;
        if (a[mid] < key) lo = mid + 1; else hi = mid;
    }
    return lo;
}

// In-wave segment bounds: lanes 0-31 chase start(g), lanes 32-63 chase end(g)
// concurrently, then shuffle-broadcast.
__device__ __forceinline__ void wave_seg_bounds(const int* __restrict__ b, int n,
                                                int g, int lane, int& s, int& e) {
    int key = g + ((lane >= 32) ? 1 : 0);
    int lo = lower_bound_i32(b, n, key);
    s = __shfl(lo, 0, 64);
    e = __shfl(lo, 32, 64);
}

__device__ __forceinline__ void f4_add(float4& a, const float4 v) {
    a.x += v.x; a.y += v.y; a.z += v.z; a.w += v.w;
}

__device__ __forceinline__ void f4_shfl_xor_add(float4& a, int mask) {
    a.x += __shfl_xor(a.x, mask, 64);
    a.y += __shfl_xor(a.y, mask, 64);
    a.z += __shfl_xor(a.z, mask, 64);
    a.w += __shfl_xor(a.w, mask, 64);
}

// KM mega-kernel:
//  blocks [0,FOLD_BLOCKS):  Wc[k][j] = embedder_row(k) . W1 block (unroll 16)
//  blocks beyond: t = blk-FOLD_BLOCKS; (t&1)==0 -> EDGE means else NODE means,
//  parity-interleaved so latency-bound gather waves co-reside with BW-bound
//  streaming waves; graph-block = t>>1, wave per graph (4 graphs/block).
//  EDGE: lane = eo(0..7)*8 + p*4 + quad. Lane owns 4 consecutive edges
//    (base = s+eo*4, stride 32): 4 idx + 4 row gathers in flight per trip,
//    32 edges per wave-trip. Quad shares a 64-B row (16 lines/instr).
//  NODE: lane = row_off*4+quad, 2 chains (i, i+16; stride 32), coalesced.
__global__ __launch_bounds__(256) void km_mega(
    const float* __restrict__ h_node,
    const int* __restrict__ bnode, const int* __restrict__ bedge,
    const int* __restrict__ esrc, const int* __restrict__ edst,
    const float* __restrict__ Wn, const float* __restrict__ We,
    const float* __restrict__ W1,
    float* __restrict__ nm, float* __restrict__ em, float* __restrict__ Wc) {
    int blk  = blockIdx.x;
    int wave = threadIdx.x >> 6;
    int lane = threadIdx.x & 63;
    const float4* h4 = (const float4*)h_node;

    if (blk < FOLD_BLOCKS) {
        // ---- weight fold ----
        int o = blk * 256 + threadIdx.x;        // 0..18431 (= KC*HDIM)
        if (o >= KC * HDIM) return;
        int k = o / HDIM, j = o % HDIM;
        float acc = 0.f;
        if (k < NT) {
            const float* wr = &Wn[k * NODE_DIM_C];
            #pragma unroll 16
            for (int kk = 0; kk < NODE_DIM_C; ++kk)
                acc = fmaf(wr[kk], W1[(size_t)kk * HDIM + j], acc);
        } else {
            const float* wr = &We[(k - NT) * EDGE_DIM_C];
            #pragma unroll 16
            for (int kk = 0; kk < EDGE_DIM_C; ++kk)
                acc = fmaf(wr[kk], W1[(size_t)(NODE_DIM_C + kk) * HDIM + j], acc);
        }
        Wc[o] = acc;
        return;
    }

    int t  = blk - FOLD_BLOCKS;
    int gb = t >> 1;                 // graph-block 0..2047

    if ((t & 1) == 0) {
        // ---- edge means ----
        int g = gb * 4 + wave;
        int s, e;
        wave_seg_bounds(bedge, N_EDGES_C, g, lane, s, e);
        int eo   = lane >> 3;          // 0..7 edge group
        int p    = (lane >> 2) & 1;    // 0=src 1=dst
        int quad = lane & 3;           // 16 B quarter of the 64-B row
        const int* __restrict__ idxp = p ? edst : esrc;
        float4 a0 = make_float4(0.f, 0.f, 0.f, 0.f);
        float4 a1 = a0, a2 = a0, a3 = a0;
        int base = s + (eo << 2);      // lane's 4 consecutive edges, stride 32
        for (int i = base; i < e; i += 32) {
            int v0 = idxp[i];
            float4 r0 = h4[(size_t)v0 * 4 + quad];
            f4_add(a0, r0);
            if (i + 1 < e) {
                int v1 = idxp[i + 1];
                f4_add(a1, h4[(size_t)v1 * 4 + quad]);
            }
            if (i + 2 < e) {
                int v2 = idxp[i + 2];
                f4_add(a2, h4[(size_t)v2 * 4 + quad]);
            }
            if (i + 3 < e) {
                int v3 = idxp[i + 3];
                f4_add(a3, h4[(size_t)v3 * 4 + quad]);
            }
        }
        f4_add(a0, a1); f4_add(a2, a3); f4_add(a0, a2);
        // reduce over eo (lane bits 3..5)
        f4_shfl_xor_add(a0, 8);
        f4_shfl_xor_add(a0, 16);
        f4_shfl_xor_add(a0, 32);
        if (eo == 0) {
            float inv = 1.f / fmaxf((float)(e - s), 1.f);
            // em row = 32 floats: quads 0..3 = src half, 4..7 = dst half
            ((float4*)em)[(size_t)g * 8 + p * 4 + quad] =
                make_float4(a0.x * inv, a0.y * inv, a0.z * inv, a0.w * inv);
        }
    } else {
        // ---- node means ----
        int g = gb * 4 + wave;
        int s, e;
        wave_seg_bounds(bnode, N_NODES_C, g, lane, s, e);
        int row_off = lane >> 2;   // 0..15
        int quad    = lane & 3;    // 0..3
        float4 a0 = make_float4(0.f, 0.f, 0.f, 0.f);
        float4 a1 = a0;
        int i = s + row_off;
        for (; i + 16 < e; i += 32) {
            float4 v0 = h4[(size_t)i * 4 + quad];
            float4 v1 = h4[(size_t)(i + 16) * 4 + quad];
            f4_add(a0, v0);
            f4_add(a1, v1);
        }
        if (i < e) f4_add(a0, h4[(size_t)i * 4 + quad]);
        f4_add(a0, a1);
        f4_shfl_xor_add(a0, 4);
        f4_shfl_xor_add(a0, 8);
        f4_shfl_xor_add(a0, 16);
        f4_shfl_xor_add(a0, 32);
        if (row_off == 0) {
            float inv = 1.f / fmaxf((float)(e - s), 1.f);
            ((float4*)nm)[(size_t)g * 4 + quad] =
                make_float4(a0.x * inv, a0.y * inv, a0.z * inv, a0.w * inv);
        }
    }
}

// K3: fused MLP.  pred[g] = relu(f[g] @ Wc + b1) . W2 + b2,  f = [nm | em] (48)
// 384 threads (thread owns column j of Wc in registers), 16 graphs / block.
#define GPB 16
__global__ __launch_bounds__(HDIM) void k3_mlp(
    const float* __restrict__ nm, const float* __restrict__ em,
    const float* __restrict__ Wc, const float* __restrict__ b1,
    const float* __restrict__ W2, const float* __restrict__ b2,
    float* __restrict__ pred) {
    int j = threadIdx.x;
    float wc[KC];
    #pragma unroll
    for (int k = 0; k < KC; ++k) wc[k] = Wc[k * HDIM + j];
    float b1j = b1[j], w2j = W2[j], b20 = b2[0];

    __shared__ float fs[GPB][KC];
    __shared__ float part[GPB][6];
    int g0 = blockIdx.x * GPB;
    #pragma unroll
    for (int t = j; t < GPB * KC; t += HDIM) {
        int g = t / KC, k = t % KC;
        fs[g][k] = (k < NT) ? nm[(size_t)(g0 + g) * NT + k]
                            : em[(size_t)(g0 + g) * 32 + (k - NT)];
    }
    __syncthreads();

    int wave = j >> 6, lane = j & 63;
    for (int g = 0; g < GPB; ++g) {
        float z = b1j;
        #pragma unroll
        for (int k = 0; k < KC; ++k) z = fmaf(fs[g][k], wc[k], z);
        z = fmaxf(z, 0.f);
        float p = z * w2j;
        #pragma unroll
        for (int off = 32; off > 0; off >>= 1) p += __shfl_down(p, off, 64);
        if (lane == 0) part[g][wave] = p;
    }
    __syncthreads();
    if (j < GPB) {
        float sacc = b20;
        #pragma unroll
        for (int w = 0; w < 6; ++w) sacc += part[j][w];
        pred[g0 + j] = sacc;
    }
}

extern "C" void kernel_launch(void* const* d_in, const int* in_sizes, int n_in,
                              void* d_out, int out_size, void* d_ws, size_t ws_size,
                              hipStream_t stream) {
    const float* h_node     = (const float*)d_in[0];
    // d_in[1] = pos_node (unused)
    const int*   batch_node = (const int*)d_in[2];
    const int*   edge_index = (const int*)d_in[3];   // [2, E] row-major
    const int*   batch_edge = (const int*)d_in[4];
    const float* W_node     = (const float*)d_in[5];
    const float* W_edge     = (const float*)d_in[6];
    const float* W1         = (const float*)d_in[7];
    const float* b1         = (const float*)d_in[8];
    const float* W2         = (const float*)d_in[9];
    const float* b2         = (const float*)d_in[10];
    float* pred = (float*)d_out;

    char* ws = (char*)d_ws;
    float* nm = (float*)(ws + WS_NM);
    float* em = (float*)(ws + WS_EM);
    float* Wc = (float*)(ws + WS_WC);

    const int* esrc = edge_index;
    const int* edst = edge_index + N_EDGES_C;

    // KM: fold (72) + parity-interleaved edge/node means (4096); in-wave bounds
    km_mega<<<TOTAL_BLOCKS, 256, 0, stream>>>(
        h_node, batch_node, batch_edge, esrc, edst, W_node, W_edge, W1, nm, em, Wc);
    // K3: fused folded MLP
    k3_mlp<<<NUM_GRAPHS_C / GPB, HDIM, 0, stream>>>(nm, em, Wc, b1, W2, b2, pred);
}

// Round 8
// 152.743 us; speedup vs baseline: 1.0895x; 1.0895x over previous
//
#include <hip/hip_runtime.h>

#define N_NODES_C   524288
#define N_EDGES_C   786432
#define NUM_GRAPHS_C 8192
#define NT 16          // NUM_NODE_TYPES
#define NODE_DIM_C 256
#define EDGE_DIM_C 128
#define HDIM 384       // NODE_DIM + EDGE_DIM
#define KC 48          // folded inner dim: 16 (node) + 32 (edge)

// block ranges: node streams first (warm L3 with h_node), edge gathers second,
// weight-fold last (tiny, off critical path until k3)
#define NODE_BLOCKS  2048
#define EDGE_BLOCKS  2048
#define FOLD_BLOCKS  72            // ceil(KC*HDIM / 256)
#define EDGE_BASE    NODE_BLOCKS
#define FOLD_BASE    (NODE_BLOCKS + EDGE_BLOCKS)
#define TOTAL_BLOCKS (NODE_BLOCKS + EDGE_BLOCKS + FOLD_BLOCKS)

// ---------------- workspace layout (bytes) ----------------
#define WS_NM    0                  // float[8192*16]   (node means)
#define WS_EM    524288             // float[8192*32]   (edge means)
#define WS_WC    1572864            // float[48*384]    (folded weights)

__device__ __forceinline__ int lower_bound_i32(const int* __restrict__ a, int n, int key) {
    int lo = 0, hi = n;
    while (lo < hi) {
        int mid = (lo + hi) >> 1;
        if (a[mid] < key) lo = mid + 1; else hi = mid;
    }
    return lo;
}

// In-wave segment bounds: lanes 0-31 chase start(g), lanes 32-63 chase end(g)
// concurrently, then shuffle-broadcast.
__device__ __forceinline__ void wave_seg_bounds(const int* __restrict__ b, int n,
                                                int g, int lane, int& s, int& e) {
    int key = g + ((lane >= 32) ? 1 : 0);
    int lo = lower_bound_i32(b, n, key);
    s = __shfl(lo, 0, 64);
    e = __shfl(lo, 32, 64);
}

__device__ __forceinline__ void f4_add(float4& a, const float4 v) {
    a.x += v.x; a.y += v.y; a.z += v.z; a.w += v.w;
}

__device__ __forceinline__ void f4_shfl_xor_add(float4& a, int mask) {
    a.x += __shfl_xor(a.x, mask, 64);
    a.y += __shfl_xor(a.y, mask, 64);
    a.z += __shfl_xor(a.z, mask, 64);
    a.w += __shfl_xor(a.w, mask, 64);
}

// KM mega-kernel, wave per graph (4 graphs/block) for the mean phases:
//  blocks [0,NODE_BLOCKS):      node means — streams h_node coalesced (warms L3)
//  blocks [EDGE_BASE,+2048):    edge means — lane = eo(0..7)*8 + p*4 + quad.
//     Edges processed in 16B-aligned int4 index groups: lane eo handles groups
//     G ≡ eo (mod 8); per trip one prefetched int4 idx load + 4 independent
//     row gathers (quad shares a 64-B row => 16 lines/instr). Boundary groups
//     take a guarded slow path; interior groups take the uniform fast path.
//  blocks [FOLD_BASE,+72):      Wc[k][j] = embedder_row(k) . W1 (unroll 16)
__global__ __launch_bounds__(256) void km_mega(
    const float* __restrict__ h_node,
    const int* __restrict__ bnode, const int* __restrict__ bedge,
    const int* __restrict__ esrc, const int* __restrict__ edst,
    const float* __restrict__ Wn, const float* __restrict__ We,
    const float* __restrict__ W1,
    float* __restrict__ nm, float* __restrict__ em, float* __restrict__ Wc) {
    int blk  = blockIdx.x;
    int wave = threadIdx.x >> 6;
    int lane = threadIdx.x & 63;
    const float4* h4 = (const float4*)h_node;

    if (blk < NODE_BLOCKS) {
        // ---- node means (streaming, 2 chains) ----
        int g = blk * 4 + wave;
        int s, e;
        wave_seg_bounds(bnode, N_NODES_C, g, lane, s, e);
        int row_off = lane >> 2;   // 0..15
        int quad    = lane & 3;    // 0..3
        float4 a0 = make_float4(0.f, 0.f, 0.f, 0.f);
        float4 a1 = a0;
        int i = s + row_off;
        for (; i + 16 < e; i += 32) {
            float4 v0 = h4[(size_t)i * 4 + quad];
            float4 v1 = h4[(size_t)(i + 16) * 4 + quad];
            f4_add(a0, v0);
            f4_add(a1, v1);
        }
        if (i < e) f4_add(a0, h4[(size_t)i * 4 + quad]);
        f4_add(a0, a1);
        f4_shfl_xor_add(a0, 4);
        f4_shfl_xor_add(a0, 8);
        f4_shfl_xor_add(a0, 16);
        f4_shfl_xor_add(a0, 32);
        if (row_off == 0) {
            float inv = 1.f / fmaxf((float)(e - s), 1.f);
            ((float4*)nm)[(size_t)g * 4 + quad] =
                make_float4(a0.x * inv, a0.y * inv, a0.z * inv, a0.w * inv);
        }
    } else if (blk < FOLD_BASE) {
        // ---- edge means (gather, 4 chains + int4 idx prefetch) ----
        int g = (blk - EDGE_BASE) * 4 + wave;
        int s, e;
        wave_seg_bounds(bedge, N_EDGES_C, g, lane, s, e);
        int eo   = lane >> 3;          // 0..7 group slot
        int p    = (lane >> 2) & 1;    // 0=src 1=dst
        int quad = lane & 3;           // 16 B quarter of the 64-B row
        const int*  __restrict__ idxp  = p ? edst : esrc;
        const int4* __restrict__ idx4p = (const int4*)idxp;   // 16B-aligned base
        float4 a0 = make_float4(0.f, 0.f, 0.f, 0.f);
        float4 a1 = a0, a2 = a0, a3 = a0;
        int G0 = s >> 2;
        int G1 = (e - 1) >> 2;         // inclusive; e>0 always here (s<e typical)
        int G  = G0 + eo;
        int4 nx = (G <= G1) ? idx4p[G] : make_int4(0, 0, 0, 0);
        while (G <= G1) {
            int4 cur = nx;
            int base = G << 2;
            int Gn = G + 8;
            if (Gn <= G1) nx = idx4p[Gn];          // prefetch next group
            if (base >= s && base + 3 < e) {       // fast path (interior group)
                f4_add(a0, h4[(size_t)cur.x * 4 + quad]);
                f4_add(a1, h4[(size_t)cur.y * 4 + quad]);
                f4_add(a2, h4[(size_t)cur.z * 4 + quad]);
                f4_add(a3, h4[(size_t)cur.w * 4 + quad]);
            } else {                               // boundary group
                if (base     >= s && base     < e) f4_add(a0, h4[(size_t)cur.x * 4 + quad]);
                if (base + 1 >= s && base + 1 < e) f4_add(a1, h4[(size_t)cur.y * 4 + quad]);
                if (base + 2 >= s && base + 2 < e) f4_add(a2, h4[(size_t)cur.z * 4 + quad]);
                if (base + 3 >= s && base + 3 < e) f4_add(a3, h4[(size_t)cur.w * 4 + quad]);
            }
            G = Gn;
        }
        f4_add(a0, a1); f4_add(a2, a3); f4_add(a0, a2);
        // reduce over eo (lane bits 3..5)
        f4_shfl_xor_add(a0, 8);
        f4_shfl_xor_add(a0, 16);
        f4_shfl_xor_add(a0, 32);
        if (eo == 0) {
            float inv = 1.f / fmaxf((float)(e - s), 1.f);
            // em row = 32 floats: quads 0..3 = src half, 4..7 = dst half
            ((float4*)em)[(size_t)g * 8 + p * 4 + quad] =
                make_float4(a0.x * inv, a0.y * inv, a0.z * inv, a0.w * inv);
        }
    } else {
        // ---- weight fold ----
        int o = (blk - FOLD_BASE) * 256 + threadIdx.x;   // 0..18431 (= KC*HDIM)
        if (o >= KC * HDIM) return;
        int k = o / HDIM, j = o % HDIM;
        float acc = 0.f;
        if (k < NT) {
            const float* wr = &Wn[k * NODE_DIM_C];
            #pragma unroll 16
            for (int kk = 0; kk < NODE_DIM_C; ++kk)
                acc = fmaf(wr[kk], W1[(size_t)kk * HDIM + j], acc);
        } else {
            const float* wr = &We[(k - NT) * EDGE_DIM_C];
            #pragma unroll 16
            for (int kk = 0; kk < EDGE_DIM_C; ++kk)
                acc = fmaf(wr[kk], W1[(size_t)(NODE_DIM_C + kk) * HDIM + j], acc);
        }
        Wc[o] = acc;
    }
}

// K3: fused MLP.  pred[g] = relu(f[g] @ Wc + b1) . W2 + b2,  f = [nm | em] (48)
// 384 threads (thread owns column j of Wc in registers), 16 graphs / block.
#define GPB 16
__global__ __launch_bounds__(HDIM) void k3_mlp(
    const float* __restrict__ nm, const float* __restrict__ em,
    const float* __restrict__ Wc, const float* __restrict__ b1,
    const float* __restrict__ W2, const float* __restrict__ b2,
    float* __restrict__ pred) {
    int j = threadIdx.x;
    float wc[KC];
    #pragma unroll
    for (int k = 0; k < KC; ++k) wc[k] = Wc[k * HDIM + j];
    float b1j = b1[j], w2j = W2[j], b20 = b2[0];

    __shared__ float fs[GPB][KC];
    __shared__ float part[GPB][6];
    int g0 = blockIdx.x * GPB;
    #pragma unroll
    for (int t = j; t < GPB * KC; t += HDIM) {
        int g = t / KC, k = t % KC;
        fs[g][k] = (k < NT) ? nm[(size_t)(g0 + g) * NT + k]
                            : em[(size_t)(g0 + g) * 32 + (k - NT)];
    }
    __syncthreads();

    int wave = j >> 6, lane = j & 63;
    for (int g = 0; g < GPB; ++g) {
        float z = b1j;
        #pragma unroll
        for (int k = 0; k < KC; ++k) z = fmaf(fs[g][k], wc[k], z);
        z = fmaxf(z, 0.f);
        float p = z * w2j;
        #pragma unroll
        for (int off = 32; off > 0; off >>= 1) p += __shfl_down(p, off, 64);
        if (lane == 0) part[g][wave] = p;
    }
    __syncthreads();
    if (j < GPB) {
        float sacc = b20;
        #pragma unroll
        for (int w = 0; w < 6; ++w) sacc += part[j][w];
        pred[g0 + j] = sacc;
    }
}

extern "C" void kernel_launch(void* const* d_in, const int* in_sizes, int n_in,
                              void* d_out, int out_size, void* d_ws, size_t ws_size,
                              hipStream_t stream) {
    const float* h_node     = (const float*)d_in[0];
    // d_in[1] = pos_node (unused)
    const int*   batch_node = (const int*)d_in[2];
    const int*   edge_index = (const int*)d_in[3];   // [2, E] row-major
    const int*   batch_edge = (const int*)d_in[4];
    const float* W_node     = (const float*)d_in[5];
    const float* W_edge     = (const float*)d_in[6];
    const float* W1         = (const float*)d_in[7];
    const float* b1         = (const float*)d_in[8];
    const float* W2         = (const float*)d_in[9];
    const float* b2         = (const float*)d_in[10];
    float* pred = (float*)d_out;

    char* ws = (char*)d_ws;
    float* nm = (float*)(ws + WS_NM);
    float* em = (float*)(ws + WS_EM);
    float* Wc = (float*)(ws + WS_WC);

    const int* esrc = edge_index;
    const int* edst = edge_index + N_EDGES_C;

    // KM: node streams (warm L3) -> edge gathers -> weight fold
    km_mega<<<TOTAL_BLOCKS, 256, 0, stream>>>(
        h_node, batch_node, batch_edge, esrc, edst, W_node, W_edge, W1, nm, em, Wc);
    // K3: fused folded MLP
    k3_mlp<<<NUM_GRAPHS_C / GPB, HDIM, 0, stream>>>(nm, em, Wc, b1, W2, b2, pred);
}

// Round 10
// 152.064 us; speedup vs baseline: 1.0944x; 1.0045x over previous
//
#include <hip/hip_runtime.h>

#define N_NODES_C   524288
#define N_EDGES_C   786432
#define NUM_GRAPHS_C 8192
#define NT 16          // NUM_NODE_TYPES
#define NODE_DIM_C 256
#define EDGE_DIM_C 128
#define HDIM 384       // NODE_DIM + EDGE_DIM
#define KC 48          // folded inner dim: 16 (node) + 32 (edge)

// block ranges: EDGE gathers first (latency-bound long poles start early),
// node streams second (BW-bound, fills in behind), weight-fold last.
// Phase code identical to R8 (correctness-verified); only ordering differs.
#define EDGE_BLOCKS  2048          // 4 graphs/block, wave per graph
#define NODE_BLOCKS  2048          // 4 graphs/block, wave per graph
#define FOLD_BLOCKS  72            // ceil(KC*HDIM / 256)
#define NODE_BASE    EDGE_BLOCKS
#define FOLD_BASE    (EDGE_BLOCKS + NODE_BLOCKS)
#define TOTAL_BLOCKS (EDGE_BLOCKS + NODE_BLOCKS + FOLD_BLOCKS)

// ---------------- workspace layout (bytes) ----------------
#define WS_NM    0                  // float[8192*16]   (node means)
#define WS_EM    524288             // float[8192*32]   (edge means)
#define WS_WC    1572864            // float[48*384]    (folded weights)

__device__ __forceinline__ int lower_bound_i32(const int* __restrict__ a, int n, int key) {
    int lo = 0, hi = n;
    while (lo < hi) {
        int mid = (lo + hi) >> 1;
        if (a[mid] < key) lo = mid + 1; else hi = mid;
    }
    return lo;
}

// In-wave segment bounds: lanes 0-31 chase start(g), lanes 32-63 chase end(g)
// concurrently, then shuffle-broadcast.
__device__ __forceinline__ void wave_seg_bounds(const int* __restrict__ b, int n,
                                                int g, int lane, int& s, int& e) {
    int key = g + ((lane >= 32) ? 1 : 0);
    int lo = lower_bound_i32(b, n, key);
    s = __shfl(lo, 0, 64);
    e = __shfl(lo, 32, 64);
}

__device__ __forceinline__ void f4_add(float4& a, const float4 v) {
    a.x += v.x; a.y += v.y; a.z += v.z; a.w += v.w;
}

__device__ __forceinline__ void f4_shfl_xor_add(float4& a, int mask) {
    a.x += __shfl_xor(a.x, mask, 64);
    a.y += __shfl_xor(a.y, mask, 64);
    a.z += __shfl_xor(a.z, mask, 64);
    a.w += __shfl_xor(a.w, mask, 64);
}

// KM mega-kernel, wave per graph (4 graphs/block) for the mean phases:
//  blocks [0,EDGE_BLOCKS):   edge means — lane = eo(0..7)*8 + p*4 + quad.
//     Edges in 16B-aligned int4 index groups: lane eo handles groups
//     G ≡ eo (mod 8); per trip one prefetched int4 idx load + 4 independent
//     row gathers (quad shares a 64-B row => 16 lines/instr). Boundary groups
//     take a guarded slow path; interior groups take the uniform fast path.
//  blocks [NODE_BASE,+2048): node means — streams h_node coalesced, 2 chains.
//  blocks [FOLD_BASE,+72):   Wc[k][j] = embedder_row(k) . W1 (unroll 16)
__global__ __launch_bounds__(256) void km_mega(
    const float* __restrict__ h_node,
    const int* __restrict__ bnode, const int* __restrict__ bedge,
    const int* __restrict__ esrc, const int* __restrict__ edst,
    const float* __restrict__ Wn, const float* __restrict__ We,
    const float* __restrict__ W1,
    float* __restrict__ nm, float* __restrict__ em, float* __restrict__ Wc) {
    int blk  = blockIdx.x;
    int wave = threadIdx.x >> 6;
    int lane = threadIdx.x & 63;
    const float4* h4 = (const float4*)h_node;

    if (blk < EDGE_BLOCKS) {
        // ---- edge means (gather, 4 chains + int4 idx prefetch) ----
        int g = blk * 4 + wave;
        int s, e;
        wave_seg_bounds(bedge, N_EDGES_C, g, lane, s, e);
        int eo   = lane >> 3;          // 0..7 group slot
        int p    = (lane >> 2) & 1;    // 0=src 1=dst
        int quad = lane & 3;           // 16 B quarter of the 64-B row
        const int*  __restrict__ idxp  = p ? edst : esrc;
        const int4* __restrict__ idx4p = (const int4*)idxp;   // 16B-aligned base
        float4 a0 = make_float4(0.f, 0.f, 0.f, 0.f);
        float4 a1 = a0, a2 = a0, a3 = a0;
        int G0 = s >> 2;
        int G1 = (e - 1) >> 2;         // inclusive (loop skipped when s==e)
        int G  = G0 + eo;
        int4 nx = (G <= G1) ? idx4p[G] : make_int4(0, 0, 0, 0);
        while (G <= G1) {
            int4 cur = nx;
            int base = G << 2;
            int Gn = G + 8;
            if (Gn <= G1) nx = idx4p[Gn];          // prefetch next group
            if (base >= s && base + 3 < e) {       // fast path (interior group)
                f4_add(a0, h4[(size_t)cur.x * 4 + quad]);
                f4_add(a1, h4[(size_t)cur.y * 4 + quad]);
                f4_add(a2, h4[(size_t)cur.z * 4 + quad]);
                f4_add(a3, h4[(size_t)cur.w * 4 + quad]);
            } else {                               // boundary group
                if (base     >= s && base     < e) f4_add(a0, h4[(size_t)cur.x * 4 + quad]);
                if (base + 1 >= s && base + 1 < e) f4_add(a1, h4[(size_t)cur.y * 4 + quad]);
                if (base + 2 >= s && base + 2 < e) f4_add(a2, h4[(size_t)cur.z * 4 + quad]);
                if (base + 3 >= s && base + 3 < e) f4_add(a3, h4[(size_t)cur.w * 4 + quad]);
            }
            G = Gn;
        }
        f4_add(a0, a1); f4_add(a2, a3); f4_add(a0, a2);
        // reduce over eo (lane bits 3..5)
        f4_shfl_xor_add(a0, 8);
        f4_shfl_xor_add(a0, 16);
        f4_shfl_xor_add(a0, 32);
        if (eo == 0) {
            float inv = 1.f / fmaxf((float)(e - s), 1.f);
            // em row = 32 floats: quads 0..3 = src half, 4..7 = dst half
            ((float4*)em)[(size_t)g * 8 + p * 4 + quad] =
                make_float4(a0.x * inv, a0.y * inv, a0.z * inv, a0.w * inv);
        }
    } else if (blk < FOLD_BASE) {
        // ---- node means (streaming, 2 chains) ----
        int g = (blk - NODE_BASE) * 4 + wave;
        int s, e;
        wave_seg_bounds(bnode, N_NODES_C, g, lane, s, e);
        int row_off = lane >> 2;   // 0..15
        int quad    = lane & 3;    // 0..3
        float4 a0 = make_float4(0.f, 0.f, 0.f, 0.f);
        float4 a1 = a0;
        int i = s + row_off;
        for (; i + 16 < e; i += 32) {
            float4 v0 = h4[(size_t)i * 4 + quad];
            float4 v1 = h4[(size_t)(i + 16) * 4 + quad];
            f4_add(a0, v0);
            f4_add(a1, v1);
        }
        if (i < e) f4_add(a0, h4[(size_t)i * 4 + quad]);
        f4_add(a0, a1);
        f4_shfl_xor_add(a0, 4);
        f4_shfl_xor_add(a0, 8);
        f4_shfl_xor_add(a0, 16);
        f4_shfl_xor_add(a0, 32);
        if (row_off == 0) {
            float inv = 1.f / fmaxf((float)(e - s), 1.f);
            ((float4*)nm)[(size_t)g * 4 + quad] =
                make_float4(a0.x * inv, a0.y * inv, a0.z * inv, a0.w * inv);
        }
    } else {
        // ---- weight fold ----
        int o = (blk - FOLD_BASE) * 256 + threadIdx.x;   // 0..18431 (= KC*HDIM)
        if (o >= KC * HDIM) return;
        int k = o / HDIM, j = o % HDIM;
        float acc = 0.f;
        if (k < NT) {
            const float* wr = &Wn[k * NODE_DIM_C];
            #pragma unroll 16
            for (int kk = 0; kk < NODE_DIM_C; ++kk)
                acc = fmaf(wr[kk], W1[(size_t)kk * HDIM + j], acc);
        } else {
            const float* wr = &We[(k - NT) * EDGE_DIM_C];
            #pragma unroll 16
            for (int kk = 0; kk < EDGE_DIM_C; ++kk)
                acc = fmaf(wr[kk], W1[(size_t)(NODE_DIM_C + kk) * HDIM + j], acc);
        }
        Wc[o] = acc;
    }
}

// K3: fused MLP.  pred[g] = relu(f[g] @ Wc + b1) . W2 + b2,  f = [nm | em] (48)
// 384 threads (thread owns column j of Wc in registers), 16 graphs / block.
#define GPB 16
__global__ __launch_bounds__(HDIM) void k3_mlp(
    const float* __restrict__ nm, const float* __restrict__ em,
    const float* __restrict__ Wc, const float* __restrict__ b1,
    const float* __restrict__ W2, const float* __restrict__ b2,
    float* __restrict__ pred) {
    int j = threadIdx.x;
    float wc[KC];
    #pragma unroll
    for (int k = 0; k < KC; ++k) wc[k] = Wc[k * HDIM + j];
    float b1j = b1[j], w2j = W2[j], b20 = b2[0];

    __shared__ float fs[GPB][KC];
    __shared__ float part[GPB][6];
    int g0 = blockIdx.x * GPB;
    #pragma unroll
    for (int t = j; t < GPB * KC; t += HDIM) {
        int g = t / KC, k = t % KC;
        fs[g][k] = (k < NT) ? nm[(size_t)(g0 + g) * NT + k]
                            : em[(size_t)(g0 + g) * 32 + (k - NT)];
    }
    __syncthreads();

    int wave = j >> 6, lane = j & 63;
    for (int g = 0; g < GPB; ++g) {
        float z = b1j;
        #pragma unroll
        for (int k = 0; k < KC; ++k) z = fmaf(fs[g][k], wc[k], z);
        z = fmaxf(z, 0.f);
        float p = z * w2j;
        #pragma unroll
        for (int off = 32; off > 0; off >>= 1) p += __shfl_down(p, off, 64);
        if (lane == 0) part[g][wave] = p;
    }
    __syncthreads();
    if (j < GPB) {
        float sacc = b20;
        #pragma unroll
        for (int w = 0; w < 6; ++w) sacc += part[j][w];
        pred[g0 + j] = sacc;
    }
}

extern "C" void kernel_launch(void* const* d_in, const int* in_sizes, int n_in,
                              void* d_out, int out_size, void* d_ws, size_t ws_size,
                              hipStream_t stream) {
    const float* h_node     = (const float*)d_in[0];
    // d_in[1] = pos_node (unused)
    const int*   batch_node = (const int*)d_in[2];
    const int*   edge_index = (const int*)d_in[3];   // [2, E] row-major
    const int*   batch_edge = (const int*)d_in[4];
    const float* W_node     = (const float*)d_in[5];
    const float* W_edge     = (const float*)d_in[6];
    const float* W1         = (const float*)d_in[7];
    const float* b1         = (const float*)d_in[8];
    const float* W2         = (const float*)d_in[9];
    const float* b2         = (const float*)d_in[10];
    float* pred = (float*)d_out;

    char* ws = (char*)d_ws;
    float* nm = (float*)(ws + WS_NM);
    float* em = (float*)(ws + WS_EM);
    float* Wc = (float*)(ws + WS_WC);

    const int* esrc = edge_index;
    const int* edst = edge_index + N_EDGES_C;

    // KM: edge gathers first -> node streams -> weight fold
    km_mega<<<TOTAL_BLOCKS, 256, 0, stream>>>(
        h_node, batch_node, batch_edge, esrc, edst, W_node, W_edge, W1, nm, em, Wc);
    // K3: fused folded MLP
    k3_mlp<<<NUM_GRAPHS_C / GPB, HDIM, 0, stream>>>(nm, em, Wc, b1, W2, b2, pred);
}

// Round 11
// 148.104 us; speedup vs baseline: 1.1237x; 1.0267x over previous
//
#include <hip/hip_runtime.h>

#define N_NODES_C   524288
#define N_EDGES_C   786432
#define NUM_GRAPHS_C 8192
#define NT 16          // NUM_NODE_TYPES
#define NODE_DIM_C 256
#define EDGE_DIM_C 128
#define HDIM 384       // NODE_DIM + EDGE_DIM
#define KC 48          // folded inner dim: 16 (node) + 32 (edge)

#define FOLD_BLOCKS  72            // ceil(KC*HDIM / 256)
#define EDGE_BLOCKS  2048          // 4 waves/block, wave per graph
#define NODE_BLOCKS  2048
#define EDGE_BASE    FOLD_BLOCKS
#define NODE_BASE    (FOLD_BLOCKS + EDGE_BLOCKS)
#define TOTAL_BLOCKS (FOLD_BLOCKS + EDGE_BLOCKS + NODE_BLOCKS)

// ---------------- workspace layout (bytes) ----------------
#define WS_NM    0                  // float[8192*16]   (node means)
#define WS_EM    524288             // float[8192*32]   (edge means)
#define WS_WC    1572864            // float[48*384]    (folded weights)

__device__ __forceinline__ int lower_bound_i32(const int* __restrict__ a, int n, int key) {
    int lo = 0, hi = n;
    while (lo < hi) {
        int mid = (lo + hi) >> 1;
        if (a[mid] < key) lo = mid + 1; else hi = mid;
    }
    return lo;
}

// In-wave segment bounds: lanes 0-31 chase start(g), lanes 32-63 chase end(g)
// concurrently, then shuffle-broadcast.
__device__ __forceinline__ void wave_seg_bounds(const int* __restrict__ b, int n,
                                                int g, int lane, int& s, int& e) {
    int key = g + ((lane >= 32) ? 1 : 0);
    int lo = lower_bound_i32(b, n, key);
    s = __shfl(lo, 0, 64);
    e = __shfl(lo, 32, 64);
}

__device__ __forceinline__ void f4_add(float4& a, const float4 v) {
    a.x += v.x; a.y += v.y; a.z += v.z; a.w += v.w;
}

__device__ __forceinline__ void f4_shfl_xor_add(float4& a, int mask) {
    a.x += __shfl_xor(a.x, mask, 64);
    a.y += __shfl_xor(a.y, mask, 64);
    a.z += __shfl_xor(a.z, mask, 64);
    a.w += __shfl_xor(a.w, mask, 64);
}

// KM mega-kernel (R6-verified structure: km = 47 us, the measured optimum of
// the R6-R10 gather-variant family):
//  blocks [0,FOLD_BLOCKS):     Wc[k][j] = embedder_row(k) . W1 block (unroll 16)
//  blocks [EDGE_BASE,+2048):   edge means, wave/graph, in-wave bounds search.
//     lane = eo(0..7)*8 + p*4 + quad: quad shares a 64-B row (16 lines/instr,
//     each line requested exactly once), two pipelined chains (i, i+8;
//     stride 16) w/ 1-deep scalar index prefetch.
//  blocks [NODE_BASE,+2048):   node means, wave/graph, fully-coalesced float4.
__global__ __launch_bounds__(256) void km_mega(
    const float* __restrict__ h_node,
    const int* __restrict__ bnode, const int* __restrict__ bedge,
    const int* __restrict__ esrc, const int* __restrict__ edst,
    const float* __restrict__ Wn, const float* __restrict__ We,
    const float* __restrict__ W1,
    float* __restrict__ nm, float* __restrict__ em, float* __restrict__ Wc) {
    int blk  = blockIdx.x;
    int wave = threadIdx.x >> 6;
    int lane = threadIdx.x & 63;
    const float4* h4 = (const float4*)h_node;

    if (blk < FOLD_BLOCKS) {
        // ---- weight fold ----
        int o = blk * 256 + threadIdx.x;        // 0..18431 (= KC*HDIM)
        if (o >= KC * HDIM) return;
        int k = o / HDIM, j = o % HDIM;
        float acc = 0.f;
        if (k < NT) {
            const float* wr = &Wn[k * NODE_DIM_C];
            #pragma unroll 16
            for (int kk = 0; kk < NODE_DIM_C; ++kk)
                acc = fmaf(wr[kk], W1[(size_t)kk * HDIM + j], acc);
        } else {
            const float* wr = &We[(k - NT) * EDGE_DIM_C];
            #pragma unroll 16
            for (int kk = 0; kk < EDGE_DIM_C; ++kk)
                acc = fmaf(wr[kk], W1[(size_t)(NODE_DIM_C + kk) * HDIM + j], acc);
        }
        Wc[o] = acc;
    } else if (blk < NODE_BASE) {
        // ---- edge means ----
        int g = (blk - EDGE_BASE) * 4 + wave;
        int s, e;
        wave_seg_bounds(bedge, N_EDGES_C, g, lane, s, e);
        int eo   = lane >> 3;          // 0..7 edge slot
        int p    = (lane >> 2) & 1;    // 0=src 1=dst
        int quad = lane & 3;           // 16 B quarter of the 64-B row
        const int* __restrict__ idxp = p ? edst : esrc;
        float4 accA = make_float4(0.f, 0.f, 0.f, 0.f);
        float4 accB = accA;
        int iA = s + eo, iB = s + eo + 8;
        int nxA = (iA < e) ? idxp[iA] : -1;
        int nxB = (iB < e) ? idxp[iB] : -1;
        while (nxB >= 0) {             // nxB valid implies nxA valid (iA < iB)
            int idxA = nxA, idxB = nxB;
            iA += 16; iB += 16;
            nxA = (iA < e) ? idxp[iA] : -1;   // prefetch next pair (independent)
            nxB = (iB < e) ? idxp[iB] : -1;
            float4 va = h4[(size_t)idxA * 4 + quad];
            float4 vb = h4[(size_t)idxB * 4 + quad];
            accA.x += va.x; accA.y += va.y; accA.z += va.z; accA.w += va.w;
            accB.x += vb.x; accB.y += vb.y; accB.z += vb.z; accB.w += vb.w;
        }
        if (nxA >= 0) {                // at most one pending A element
            float4 v = h4[(size_t)nxA * 4 + quad];
            accA.x += v.x; accA.y += v.y; accA.z += v.z; accA.w += v.w;
        }
        accA.x += accB.x; accA.y += accB.y; accA.z += accB.z; accA.w += accB.w;
        // reduce over eo (lane bits 3..5)
        f4_shfl_xor_add(accA, 8);
        f4_shfl_xor_add(accA, 16);
        f4_shfl_xor_add(accA, 32);
        if (eo == 0) {
            float inv = 1.f / fmaxf((float)(e - s), 1.f);
            // em row = 32 floats: quads 0..3 = src half, 4..7 = dst half
            ((float4*)em)[(size_t)g * 8 + p * 4 + quad] =
                make_float4(accA.x * inv, accA.y * inv, accA.z * inv, accA.w * inv);
        }
    } else {
        // ---- node means ----
        int g = (blk - NODE_BASE) * 4 + wave;
        int s, e;
        wave_seg_bounds(bnode, N_NODES_C, g, lane, s, e);
        int row_off = lane >> 2;   // 0..15
        int quad    = lane & 3;    // 0..3
        float4 a0 = make_float4(0.f, 0.f, 0.f, 0.f);
        float4 a1 = a0;
        int i = s + row_off;
        for (; i + 16 < e; i += 32) {
            float4 v0 = h4[(size_t)i * 4 + quad];
            float4 v1 = h4[(size_t)(i + 16) * 4 + quad];
            f4_add(a0, v0);
            f4_add(a1, v1);
        }
        if (i < e) f4_add(a0, h4[(size_t)i * 4 + quad]);
        f4_add(a0, a1);
        f4_shfl_xor_add(a0, 4);
        f4_shfl_xor_add(a0, 8);
        f4_shfl_xor_add(a0, 16);
        f4_shfl_xor_add(a0, 32);
        if (row_off == 0) {
            float inv = 1.f / fmaxf((float)(e - s), 1.f);
            ((float4*)nm)[(size_t)g * 4 + quad] =
                make_float4(a0.x * inv, a0.y * inv, a0.z * inv, a0.w * inv);
        }
    }
}

// K3: fused MLP.  pred[g] = relu(f[g] @ Wc + b1) . W2 + b2,  f = [nm | em] (48)
// 384 threads (thread owns column j of Wc in registers), 16 graphs / block.
#define GPB 16
__global__ __launch_bounds__(HDIM) void k3_mlp(
    const float* __restrict__ nm, const float* __restrict__ em,
    const float* __restrict__ Wc, const float* __restrict__ b1,
    const float* __restrict__ W2, const float* __restrict__ b2,
    float* __restrict__ pred) {
    int j = threadIdx.x;
    float wc[KC];
    #pragma unroll
    for (int k = 0; k < KC; ++k) wc[k] = Wc[k * HDIM + j];
    float b1j = b1[j], w2j = W2[j], b20 = b2[0];

    __shared__ float fs[GPB][KC];
    __shared__ float part[GPB][6];
    int g0 = blockIdx.x * GPB;
    #pragma unroll
    for (int t = j; t < GPB * KC; t += HDIM) {
        int g = t / KC, k = t % KC;
        fs[g][k] = (k < NT) ? nm[(size_t)(g0 + g) * NT + k]
                            : em[(size_t)(g0 + g) * 32 + (k - NT)];
    }
    __syncthreads();

    int wave = j >> 6, lane = j & 63;
    for (int g = 0; g < GPB; ++g) {
        float z = b1j;
        #pragma unroll
        for (int k = 0; k < KC; ++k) z = fmaf(fs[g][k], wc[k], z);
        z = fmaxf(z, 0.f);
        float p = z * w2j;
        #pragma unroll
        for (int off = 32; off > 0; off >>= 1) p += __shfl_down(p, off, 64);
        if (lane == 0) part[g][wave] = p;
    }
    __syncthreads();
    if (j < GPB) {
        float sacc = b20;
        #pragma unroll
        for (int w = 0; w < 6; ++w) sacc += part[j][w];
        pred[g0 + j] = sacc;
    }
}

extern "C" void kernel_launch(void* const* d_in, const int* in_sizes, int n_in,
                              void* d_out, int out_size, void* d_ws, size_t ws_size,
                              hipStream_t stream) {
    const float* h_node     = (const float*)d_in[0];
    // d_in[1] = pos_node (unused)
    const int*   batch_node = (const int*)d_in[2];
    const int*   edge_index = (const int*)d_in[3];   // [2, E] row-major
    const int*   batch_edge = (const int*)d_in[4];
    const float* W_node     = (const float*)d_in[5];
    const float* W_edge     = (const float*)d_in[6];
    const float* W1         = (const float*)d_in[7];
    const float* b1         = (const float*)d_in[8];
    const float* W2         = (const float*)d_in[9];
    const float* b2         = (const float*)d_in[10];
    float* pred = (float*)d_out;

    char* ws = (char*)d_ws;
    float* nm = (float*)(ws + WS_NM);
    float* em = (float*)(ws + WS_EM);
    float* Wc = (float*)(ws + WS_WC);

    const int* esrc = edge_index;
    const int* edst = edge_index + N_EDGES_C;

    // KM: fold (72) + edge means (2048) + node means (2048); bounds searched in-wave
    km_mega<<<TOTAL_BLOCKS, 256, 0, stream>>>(
        h_node, batch_node, batch_edge, esrc, edst, W_node, W_edge, W1, nm, em, Wc);
    // K3: fused folded MLP
    k3_mlp<<<NUM_GRAPHS_C / GPB, HDIM, 0, stream>>>(nm, em, Wc, b1, W2, b2, pred);
}